// Round 1
// baseline (451.474 us; speedup 1.0000x reference)
//
#include <hip/hip_runtime.h>
#include <hip/hip_bf16.h>
#include <math.h>

#define HEADS 4
#define HID 32
#define FDIM 128   // HEADS*HID == IN
#define OUTC 10
#define NEG 0.2f

static __device__ __forceinline__ float lrelu(float v) { return v > 0.f ? v : NEG * v; }

// ---------------- CSR build ----------------
__global__ void k_count(const int* __restrict__ ei, int* __restrict__ deg, int E, int n) {
  int e = blockIdx.x * 256 + threadIdx.x;
  int tot = E + n;
  if (e >= tot) return;
  int dst = (e < E) ? ei[E + e] : (e - E);
  atomicAdd(&deg[dst], 1);
}

__global__ void k_scan_block(const int* __restrict__ deg, int* __restrict__ offs,
                             int* __restrict__ parts, int n) {
  __shared__ int sh[256];
  int i = blockIdx.x * 256 + threadIdx.x;
  int v = (i < n) ? deg[i] : 0;
  sh[threadIdx.x] = v;
  __syncthreads();
  #pragma unroll
  for (int off = 1; off < 256; off <<= 1) {
    int t = (threadIdx.x >= off) ? sh[threadIdx.x - off] : 0;
    __syncthreads();
    sh[threadIdx.x] += t;
    __syncthreads();
  }
  if (i < n) offs[i + 1] = sh[threadIdx.x];
  if (threadIdx.x == 255) parts[blockIdx.x] = sh[255];
}

__global__ void k_scan_parts(int* __restrict__ parts, int nb) {
  __shared__ int sh[256];
  int v = (threadIdx.x < nb) ? parts[threadIdx.x] : 0;
  sh[threadIdx.x] = v;
  __syncthreads();
  #pragma unroll
  for (int off = 1; off < 256; off <<= 1) {
    int t = (threadIdx.x >= off) ? sh[threadIdx.x - off] : 0;
    __syncthreads();
    sh[threadIdx.x] += t;
    __syncthreads();
  }
  if (threadIdx.x < nb) parts[threadIdx.x] = sh[threadIdx.x] - v;  // exclusive prefix
}

__global__ void k_add_offs(int* __restrict__ offs, const int* __restrict__ parts, int n) {
  int i = blockIdx.x * 256 + threadIdx.x;
  if (i < n) offs[i + 1] += parts[blockIdx.x];
  if (i == 0) offs[0] = 0;
}

__global__ void k_fill(const int* __restrict__ ei, const int* __restrict__ offs,
                       int* __restrict__ cursor, int* __restrict__ csr, int E, int n) {
  int e = blockIdx.x * 256 + threadIdx.x;
  int tot = E + n;
  if (e >= tot) return;
  int src = (e < E) ? ei[e] : (e - E);
  int dst = (e < E) ? ei[E + e] : (e - E);
  int pos = atomicAdd(&cursor[dst], 1);
  csr[offs[dst] + pos] = src;
}

// ---------------- GEMM + attention logits ----------------
// Block: 256 threads = 4 waves; wave w == head w; lane == row within 64-row tile.
// Each lane accumulates 32 output cols (one head) in registers. W read at
// wave-uniform addresses -> scalar loads. x tile staged in LDS (stride 132).
__global__ __launch_bounds__(256) void k_gemm_al(
    const float* __restrict__ X, const float* __restrict__ W,
    const float* __restrict__ Asrc, const float* __restrict__ Adst,
    float* __restrict__ H, float* __restrict__ alS, float* __restrict__ alD, int n) {
  __shared__ float xt[64 * 132];
  int t = threadIdx.x;
  long base = (long)blockIdx.x * 64;
  for (int i = t; i < 64 * 128; i += 256) {
    int r = i >> 7, k = i & 127;
    long row = base + r;
    xt[r * 132 + k] = (row < n) ? X[row * 128 + k] : 0.f;
  }
  __syncthreads();
  int lane = t & 63;
  int head = __builtin_amdgcn_readfirstlane(t >> 6);
  long row = base + lane;
  float acc[32];
  #pragma unroll
  for (int c = 0; c < 32; ++c) acc[c] = 0.f;
  const float* wb = W + head * 32;
  for (int k = 0; k < 128; k += 4) {
    float4 xv = *reinterpret_cast<const float4*>(&xt[lane * 132 + k]);
    #pragma unroll
    for (int kk = 0; kk < 4; ++kk) {
      float xs = (&xv.x)[kk];
      const float* wr = wb + (k + kk) * 128;
      #pragma unroll
      for (int c = 0; c < 32; ++c) acc[c] = fmaf(xs, wr[c], acc[c]);
    }
  }
  if (row < n) {
    const float* as = Asrc + head * 32;
    const float* ad = Adst + head * 32;
    float ss = 0.f, sd = 0.f;
    #pragma unroll
    for (int c = 0; c < 32; ++c) { ss = fmaf(acc[c], as[c], ss); sd = fmaf(acc[c], ad[c], sd); }
    alS[row * 4 + head] = ss;
    alD[row * 4 + head] = sd;
    float* hr = H + row * 128 + head * 32;
    #pragma unroll
    for (int c = 0; c < 32; c += 4)
      *reinterpret_cast<float4*>(hr + c) = make_float4(acc[c], acc[c+1], acc[c+2], acc[c+3]);
  }
}

// ---------------- per-dst softmax + aggregation ----------------
// One wave per destination node. Pass 1: per-head max over incoming edges.
// Pass 2: p = exp(e-m), z-sum, and feature accumulation via readlane broadcast
// + coalesced 256B gathers of h[src]. No atomics, no LDS, no barriers.
template<bool ELU_OUT>
__global__ __launch_bounds__(256) void k_agg(
    const float* __restrict__ H, const float* __restrict__ aS, const float* __restrict__ aD,
    const int* __restrict__ offs, const int* __restrict__ csr,
    const float* __restrict__ bias, float* __restrict__ OUT, int n) {
  int lane = threadIdx.x & 63;
  int dst = __builtin_amdgcn_readfirstlane(blockIdx.x * 4 + (threadIdx.x >> 6));
  if (dst >= n) return;
  int beg = offs[dst], end = offs[dst + 1];
  float ad0 = aD[(size_t)dst * 4 + 0], ad1 = aD[(size_t)dst * 4 + 1];
  float ad2 = aD[(size_t)dst * 4 + 2], ad3 = aD[(size_t)dst * 4 + 3];

  float m0 = -1e30f, m1 = -1e30f, m2 = -1e30f, m3 = -1e30f;
  float e00 = -1e30f, e01 = -1e30f, e02 = -1e30f, e03 = -1e30f;
  int s0 = 0;
  for (int cb = beg; cb < end; cb += 64) {
    int idx = cb + lane;
    float e0 = -1e30f, e1 = -1e30f, e2 = -1e30f, e3 = -1e30f;
    int s = 0;
    if (idx < end) {
      s = csr[idx];
      float4 a = *reinterpret_cast<const float4*>(aS + (size_t)s * 4);
      e0 = lrelu(a.x + ad0); e1 = lrelu(a.y + ad1);
      e2 = lrelu(a.z + ad2); e3 = lrelu(a.w + ad3);
    }
    if (cb == beg) { e00 = e0; e01 = e1; e02 = e2; e03 = e3; s0 = s; }
    m0 = fmaxf(m0, e0); m1 = fmaxf(m1, e1); m2 = fmaxf(m2, e2); m3 = fmaxf(m3, e3);
  }
  #pragma unroll
  for (int off = 32; off; off >>= 1) {
    m0 = fmaxf(m0, __shfl_xor(m0, off));
    m1 = fmaxf(m1, __shfl_xor(m1, off));
    m2 = fmaxf(m2, __shfl_xor(m2, off));
    m3 = fmaxf(m3, __shfl_xor(m3, off));
  }

  float z0 = 0.f, z1 = 0.f, z2 = 0.f, z3 = 0.f;
  float accA = 0.f, accB = 0.f;
  int hsel = lane >> 5;  // 0: heads {0,2}, 1: heads {1,3}
  for (int cb = beg; cb < end; cb += 64) {
    int idx = cb + lane;
    bool v = idx < end;
    float e0, e1, e2, e3;
    int s;
    if (cb == beg) { e0 = e00; e1 = e01; e2 = e02; e3 = e03; s = s0; }
    else {
      e0 = e1 = e2 = e3 = -1e30f; s = 0;
      if (v) {
        s = csr[idx];
        float4 a = *reinterpret_cast<const float4*>(aS + (size_t)s * 4);
        e0 = lrelu(a.x + ad0); e1 = lrelu(a.y + ad1);
        e2 = lrelu(a.z + ad2); e3 = lrelu(a.w + ad3);
      }
    }
    float p0 = v ? __expf(e0 - m0) : 0.f;
    float p1 = v ? __expf(e1 - m1) : 0.f;
    float p2 = v ? __expf(e2 - m2) : 0.f;
    float p3 = v ? __expf(e3 - m3) : 0.f;
    z0 += p0; z1 += p1; z2 += p2; z3 += p3;

    int cnt = min(64, end - cb);
    int j = 0;
    for (; j + 2 <= cnt; j += 2) {
      int sA = __shfl(s, j), sB = __shfl(s, j + 1);
      float qa0 = __shfl(p0, j), qa1 = __shfl(p1, j), qa2 = __shfl(p2, j), qa3 = __shfl(p3, j);
      float qb0 = __shfl(p0, j + 1), qb1 = __shfl(p1, j + 1), qb2 = __shfl(p2, j + 1), qb3 = __shfl(p3, j + 1);
      const float* ha = H + (size_t)sA * 128;
      const float* hb = H + (size_t)sB * 128;
      float vA0 = ha[lane], vA1 = ha[lane + 64];
      float vB0 = hb[lane], vB1 = hb[lane + 64];
      float paA = hsel ? qa1 : qa0, pbA = hsel ? qa3 : qa2;
      float paB = hsel ? qb1 : qb0, pbB = hsel ? qb3 : qb2;
      accA = fmaf(paA, vA0, accA); accB = fmaf(pbA, vA1, accB);
      accA = fmaf(paB, vB0, accA); accB = fmaf(pbB, vB1, accB);
    }
    for (; j < cnt; ++j) {
      int sA = __shfl(s, j);
      float qa0 = __shfl(p0, j), qa1 = __shfl(p1, j), qa2 = __shfl(p2, j), qa3 = __shfl(p3, j);
      const float* ha = H + (size_t)sA * 128;
      float paA = hsel ? qa1 : qa0, pbA = hsel ? qa3 : qa2;
      accA = fmaf(paA, ha[lane], accA);
      accB = fmaf(pbA, ha[lane + 64], accB);
    }
  }
  #pragma unroll
  for (int off = 32; off; off >>= 1) {
    z0 += __shfl_xor(z0, off);
    z1 += __shfl_xor(z1, off);
    z2 += __shfl_xor(z2, off);
    z3 += __shfl_xor(z3, off);
  }
  float zA = hsel ? z1 : z0;
  float zB = hsel ? z3 : z2;
  float oA = accA / (zA + 1e-16f) + bias[lane];
  float oB = accB / (zB + 1e-16f) + bias[lane + 64];
  if (ELU_OUT) {
    oA = oA > 0.f ? oA : expm1f(oA);
    oB = oB > 0.f ? oB : expm1f(oB);
  }
  OUT[(size_t)dst * 128 + lane] = oA;
  OUT[(size_t)dst * 128 + lane + 64] = oB;
}

// ---------------- pooling (batch is sorted) ----------------
__global__ __launch_bounds__(256) void k_pool(
    const float* __restrict__ X, const int* __restrict__ batch,
    float* __restrict__ pooled, int* __restrict__ gcnt, int n) {
  int lane = threadIdx.x & 63;
  int w = blockIdx.x * 4 + (threadIdx.x >> 6);
  int a = w * 64;
  if (a >= n) return;
  int b = min(a + 64, n);
  float accA = 0.f, accB = 0.f;
  int gcur = batch[a];
  int cg = 0;
  for (int node = a; node < b; ++node) {
    int g = batch[node];
    if (g != gcur) {
      atomicAdd(&pooled[(size_t)gcur * 128 + lane], accA);
      atomicAdd(&pooled[(size_t)gcur * 128 + lane + 64], accB);
      if (lane == 0) atomicAdd(&gcnt[gcur], cg);
      accA = accB = 0.f; cg = 0; gcur = g;
    }
    accA += X[(size_t)node * 128 + lane];
    accB += X[(size_t)node * 128 + lane + 64];
    ++cg;
  }
  atomicAdd(&pooled[(size_t)gcur * 128 + lane], accA);
  atomicAdd(&pooled[(size_t)gcur * 128 + lane + 64], accB);
  if (lane == 0) atomicAdd(&gcnt[gcur], cg);
}

// ---------------- classifier head ----------------
__global__ void k_head(const float* __restrict__ pooled, const int* __restrict__ gcnt,
                       const float* __restrict__ Wl, const float* __restrict__ bl,
                       float* __restrict__ out) {
  int g = blockIdx.x;
  int lane = threadIdx.x;  // 64 threads
  float cnt = fmaxf((float)gcnt[g], 1.f);
  float pA = pooled[(size_t)g * 128 + lane] / cnt;
  float pB = pooled[(size_t)g * 128 + lane + 64] / cnt;
  float l[OUTC];
  #pragma unroll
  for (int o = 0; o < OUTC; ++o) {
    float s = pA * Wl[lane * OUTC + o] + pB * Wl[(lane + 64) * OUTC + o];
    #pragma unroll
    for (int off = 32; off; off >>= 1) s += __shfl_xor(s, off);
    l[o] = s + bl[o];
  }
  float mx = l[0];
  #pragma unroll
  for (int o = 1; o < OUTC; ++o) mx = fmaxf(mx, l[o]);
  float se = 0.f;
  #pragma unroll
  for (int o = 0; o < OUTC; ++o) { l[o] = __expf(l[o] - mx); se += l[o]; }
  if (lane == 0) {
    float inv = 1.f / se;
    #pragma unroll
    for (int o = 0; o < OUTC; ++o) out[g * OUTC + o] = l[o] * inv;
  }
}

extern "C" void kernel_launch(void* const* d_in, const int* in_sizes, int n_in,
                              void* d_out, int out_size, void* d_ws, size_t ws_size,
                              hipStream_t stream) {
  const float* x   = (const float*)d_in[0];
  const float* W1  = (const float*)d_in[1];
  const float* a1s = (const float*)d_in[2];
  const float* a1d = (const float*)d_in[3];
  const float* b1  = (const float*)d_in[4];
  const float* W2  = (const float*)d_in[5];
  const float* a2s = (const float*)d_in[6];
  const float* a2d = (const float*)d_in[7];
  const float* b2  = (const float*)d_in[8];
  const float* Wl  = (const float*)d_in[9];
  const float* bl  = (const float*)d_in[10];
  const int* ei    = (const int*)d_in[11];
  const int* batch = (const int*)d_in[12];
  const int N = in_sizes[12];
  const int E = in_sizes[11] / 2;
  const int G = out_size / OUTC;
  float* out = (float*)d_out;
  (void)n_in; (void)ws_size;

  char* w = (char*)d_ws;
  auto alloc = [&](size_t bytes) { char* p = w; w += (bytes + 255) & ~(size_t)255; return (void*)p; };
  float* H      = (float*)alloc((size_t)N * FDIM * sizeof(float));
  float* ACT    = (float*)alloc((size_t)N * FDIM * sizeof(float));
  float* AS     = (float*)alloc((size_t)N * HEADS * sizeof(float));
  float* AD     = (float*)alloc((size_t)N * HEADS * sizeof(float));
  int*   deg    = (int*)alloc((size_t)N * sizeof(int));
  int*   offs   = (int*)alloc((size_t)(N + 1) * sizeof(int));
  int*   cur    = (int*)alloc((size_t)N * sizeof(int));
  int*   csr    = (int*)alloc((size_t)(E + N) * sizeof(int));
  int*   parts  = (int*)alloc(256 * sizeof(int));
  float* pooled = (float*)alloc((size_t)G * FDIM * sizeof(float));
  int*   gcnt   = (int*)alloc((size_t)G * sizeof(int));

  hipMemsetAsync(deg, 0, (size_t)N * sizeof(int), stream);
  hipMemsetAsync(cur, 0, (size_t)N * sizeof(int), stream);
  hipMemsetAsync(pooled, 0, (size_t)G * FDIM * sizeof(float), stream);
  hipMemsetAsync(gcnt, 0, (size_t)G * sizeof(int), stream);

  int tot = E + N;
  int eb = (tot + 255) / 256;
  int nb = (N + 255) / 256;
  k_count<<<eb, 256, 0, stream>>>(ei, deg, E, N);
  k_scan_block<<<nb, 256, 0, stream>>>(deg, offs, parts, N);
  k_scan_parts<<<1, 256, 0, stream>>>(parts, nb);
  k_add_offs<<<nb, 256, 0, stream>>>(offs, parts, N);
  k_fill<<<eb, 256, 0, stream>>>(ei, offs, cur, csr, E, N);

  int gb = (N + 63) / 64;
  int ab = (N + 3) / 4;
  k_gemm_al<<<gb, 256, 0, stream>>>(x, W1, a1s, a1d, H, AS, AD, N);
  k_agg<true><<<ab, 256, 0, stream>>>(H, AS, AD, offs, csr, b1, ACT, N);
  k_gemm_al<<<gb, 256, 0, stream>>>(ACT, W2, a2s, a2d, H, AS, AD, N);
  k_agg<false><<<ab, 256, 0, stream>>>(H, AS, AD, offs, csr, b2, ACT, N);

  int pb = (N + 255) / 256;
  k_pool<<<pb, 256, 0, stream>>>(ACT, batch, pooled, gcnt, N);
  k_head<<<G, 64, 0, stream>>>(pooled, gcnt, Wl, bl, out);
}

// Round 2
// 403.311 us; speedup vs baseline: 1.1194x; 1.1194x over previous
//
#include <hip/hip_runtime.h>
#include <hip/hip_bf16.h>
#include <math.h>

#define HEADS 4
#define HID 32
#define FDIM 128   // HEADS*HID == IN
#define OUTC 10
#define NEG 0.2f

static __device__ __forceinline__ float lrelu(float v) { return v > 0.f ? v : NEG * v; }

// round-to-nearest-even f32 -> bf16 (returns low 16 bits)
static __device__ __forceinline__ unsigned bfr(float f) {
  unsigned u = __float_as_uint(f);
  return (u + 0x7fffu + ((u >> 16) & 1u)) >> 16;
}
static __device__ __forceinline__ float blo(unsigned u) { return __uint_as_float(u << 16); }
static __device__ __forceinline__ float bhi(unsigned u) { return __uint_as_float(u & 0xffff0000u); }

// ---------------- CSR build ----------------
__global__ void k_count(const int* __restrict__ ei, int* __restrict__ deg, int E, int n) {
  int e = blockIdx.x * 256 + threadIdx.x;
  int tot = E + n;
  if (e >= tot) return;
  int dst = (e < E) ? ei[E + e] : (e - E);
  atomicAdd(&deg[dst], 1);
}

__global__ void k_scan_block(const int* __restrict__ deg, int* __restrict__ offs,
                             int* __restrict__ parts, int n) {
  __shared__ int sh[256];
  int i = blockIdx.x * 256 + threadIdx.x;
  int v = (i < n) ? deg[i] : 0;
  sh[threadIdx.x] = v;
  __syncthreads();
  #pragma unroll
  for (int off = 1; off < 256; off <<= 1) {
    int t = (threadIdx.x >= off) ? sh[threadIdx.x - off] : 0;
    __syncthreads();
    sh[threadIdx.x] += t;
    __syncthreads();
  }
  if (i < n) offs[i + 1] = sh[threadIdx.x];
  if (threadIdx.x == 255) parts[blockIdx.x] = sh[255];
}

__global__ void k_scan_parts(int* __restrict__ parts, int nb) {
  __shared__ int sh[256];
  int v = (threadIdx.x < nb) ? parts[threadIdx.x] : 0;
  sh[threadIdx.x] = v;
  __syncthreads();
  #pragma unroll
  for (int off = 1; off < 256; off <<= 1) {
    int t = (threadIdx.x >= off) ? sh[threadIdx.x - off] : 0;
    __syncthreads();
    sh[threadIdx.x] += t;
    __syncthreads();
  }
  if (threadIdx.x < nb) parts[threadIdx.x] = sh[threadIdx.x] - v;  // exclusive prefix
}

__global__ void k_add_offs(int* __restrict__ offs, const int* __restrict__ parts, int n) {
  int i = blockIdx.x * 256 + threadIdx.x;
  if (i < n) offs[i + 1] += parts[blockIdx.x];
  if (i == 0) offs[0] = 0;
}

__global__ void k_fill(const int* __restrict__ ei, const int* __restrict__ offs,
                       int* __restrict__ cursor, int* __restrict__ csr, int E, int n) {
  int e = blockIdx.x * 256 + threadIdx.x;
  int tot = E + n;
  if (e >= tot) return;
  int src = (e < E) ? ei[e] : (e - E);
  int dst = (e < E) ? ei[E + e] : (e - E);
  int pos = atomicAdd(&cursor[dst], 1);
  csr[offs[dst] + pos] = src;
}

// ---------------- GEMM + attention logits ----------------
// Block: 256 threads = 4 waves; wave w == head w; lane == row within 64-row tile.
// Each lane accumulates 32 output cols (one head) in registers. W read at
// wave-uniform addresses -> scalar loads. x tile staged in LDS (stride 132).
// H written as bf16 (aggregation gathers it; tolerance is bf16-grade).
__global__ __launch_bounds__(256) void k_gemm_al(
    const float* __restrict__ X, const float* __restrict__ W,
    const float* __restrict__ Asrc, const float* __restrict__ Adst,
    __hip_bfloat16* __restrict__ H, float* __restrict__ alS, float* __restrict__ alD, int n) {
  __shared__ float xt[64 * 132];
  int t = threadIdx.x;
  long base = (long)blockIdx.x * 64;
  for (int i = t; i < 64 * 128; i += 256) {
    int r = i >> 7, k = i & 127;
    long row = base + r;
    xt[r * 132 + k] = (row < n) ? X[row * 128 + k] : 0.f;
  }
  __syncthreads();
  int lane = t & 63;
  int head = __builtin_amdgcn_readfirstlane(t >> 6);
  long row = base + lane;
  float acc[32];
  #pragma unroll
  for (int c = 0; c < 32; ++c) acc[c] = 0.f;
  const float* wb = W + head * 32;
  for (int k = 0; k < 128; k += 4) {
    float4 xv = *reinterpret_cast<const float4*>(&xt[lane * 132 + k]);
    #pragma unroll
    for (int kk = 0; kk < 4; ++kk) {
      float xs = (&xv.x)[kk];
      const float* wr = wb + (k + kk) * 128;
      #pragma unroll
      for (int c = 0; c < 32; ++c) acc[c] = fmaf(xs, wr[c], acc[c]);
    }
  }
  if (row < n) {
    const float* as = Asrc + head * 32;
    const float* ad = Adst + head * 32;
    float ss = 0.f, sd = 0.f;
    #pragma unroll
    for (int c = 0; c < 32; ++c) { ss = fmaf(acc[c], as[c], ss); sd = fmaf(acc[c], ad[c], sd); }
    alS[row * 4 + head] = ss;
    alD[row * 4 + head] = sd;
    // pack 32 f32 -> 32 bf16 -> 4 x uint4 stores
    uint4* hr = reinterpret_cast<uint4*>(H) + row * 16 + head * 4;
    #pragma unroll
    for (int q = 0; q < 4; ++q) {
      uint4 pk;
      pk.x = bfr(acc[q * 8 + 0]) | (bfr(acc[q * 8 + 1]) << 16);
      pk.y = bfr(acc[q * 8 + 2]) | (bfr(acc[q * 8 + 3]) << 16);
      pk.z = bfr(acc[q * 8 + 4]) | (bfr(acc[q * 8 + 5]) << 16);
      pk.w = bfr(acc[q * 8 + 6]) | (bfr(acc[q * 8 + 7]) << 16);
      hr[q] = pk;
    }
  }
}

// ---------------- per-dst softmax + aggregation ----------------
// One wave per destination node. Pass 1: per-head max over incoming edges
// (edge-parallel, butterfly reduce). Pass 2 per 64-edge chunk: compute
// p = exp(e-m) edge-parallel, stash (p[4], src) in wave-private LDS, then
// gather feature-parallel: lane = (edge quarter, feature octet); one
// global_load_dwordx4 covers 8 bf16 features of one edge's h-row; 4 edges
// per instruction, unrolled x2 for 2 loads in flight. No atomics/barriers.
template<bool ELU_OUT>
__global__ __launch_bounds__(256) void k_agg(
    const __hip_bfloat16* __restrict__ H, const float* __restrict__ aS,
    const float* __restrict__ aD,
    const int* __restrict__ offs, const int* __restrict__ csr,
    const float* __restrict__ bias, float* __restrict__ OUT, int n) {
  __shared__ int s_l[4][64];
  __shared__ float p_l[4][64 * 4];
  int lane = threadIdx.x & 63;
  int wid = threadIdx.x >> 6;
  int dst = __builtin_amdgcn_readfirstlane(blockIdx.x * 4 + wid);
  if (dst >= n) return;
  int* s_w = s_l[wid];
  float* p_w = p_l[wid];
  int beg = offs[dst], end = offs[dst + 1];
  float4 adv = *reinterpret_cast<const float4*>(aD + (size_t)dst * 4);

  // ---- pass 1: per-head max ----
  float m0 = -1e30f, m1 = -1e30f, m2 = -1e30f, m3 = -1e30f;
  float e00 = -1e30f, e01 = -1e30f, e02 = -1e30f, e03 = -1e30f;
  int s0v = 0;
  for (int cb = beg; cb < end; cb += 64) {
    int idx = cb + lane;
    float e0 = -1e30f, e1 = -1e30f, e2 = -1e30f, e3 = -1e30f;
    int s = 0;
    if (idx < end) {
      s = csr[idx];
      float4 a = *reinterpret_cast<const float4*>(aS + (size_t)s * 4);
      e0 = lrelu(a.x + adv.x); e1 = lrelu(a.y + adv.y);
      e2 = lrelu(a.z + adv.z); e3 = lrelu(a.w + adv.w);
    }
    if (cb == beg) { e00 = e0; e01 = e1; e02 = e2; e03 = e3; s0v = s; }
    m0 = fmaxf(m0, e0); m1 = fmaxf(m1, e1); m2 = fmaxf(m2, e2); m3 = fmaxf(m3, e3);
  }
  #pragma unroll
  for (int off = 32; off; off >>= 1) {
    m0 = fmaxf(m0, __shfl_xor(m0, off));
    m1 = fmaxf(m1, __shfl_xor(m1, off));
    m2 = fmaxf(m2, __shfl_xor(m2, off));
    m3 = fmaxf(m3, __shfl_xor(m3, off));
  }

  // ---- pass 2: p, z, feature gather ----
  float z0 = 0.f, z1 = 0.f, z2 = 0.f, z3 = 0.f;
  float acc[8];
  #pragma unroll
  for (int k = 0; k < 8; ++k) acc[k] = 0.f;
  int fl = lane & 15;        // feature octet index (8 floats each)
  int qw = lane >> 4;        // quarter-wave = edge slot within group of 4
  int hsel = fl >> 2;        // head for this feature octet
  const uint4* hb = reinterpret_cast<const uint4*>(H) + fl;

  for (int cb = beg; cb < end; cb += 64) {
    int idx = cb + lane;
    bool v = idx < end;
    float e0, e1, e2, e3;
    int s;
    if (cb == beg) { e0 = e00; e1 = e01; e2 = e02; e3 = e03; s = s0v; }
    else {
      e0 = e1 = e2 = e3 = -1e30f; s = 0;
      if (v) {
        s = csr[idx];
        float4 a = *reinterpret_cast<const float4*>(aS + (size_t)s * 4);
        e0 = lrelu(a.x + adv.x); e1 = lrelu(a.y + adv.y);
        e2 = lrelu(a.z + adv.z); e3 = lrelu(a.w + adv.w);
      }
    }
    float p0 = v ? __expf(e0 - m0) : 0.f;
    float p1 = v ? __expf(e1 - m1) : 0.f;
    float p2 = v ? __expf(e2 - m2) : 0.f;
    float p3 = v ? __expf(e3 - m3) : 0.f;
    z0 += p0; z1 += p1; z2 += p2; z3 += p3;

    s_w[lane] = s;
    *reinterpret_cast<float4*>(&p_w[lane * 4]) = make_float4(p0, p1, p2, p3);
    // wave-private LDS: compiler inserts lgkmcnt wait; no barrier needed

    int cnt = min(64, end - cb);
    int git = (cnt + 7) >> 3;
    for (int it = 0; it < git; ++it) {
      int jA = it * 8 + qw;
      int jB = jA + 4;
      bool vA = jA < cnt, vB = jB < cnt;
      int jAc = vA ? jA : 0;
      int jBc = vB ? jB : 0;
      int sA = s_w[jAc];
      int sB = s_w[jBc];
      float pA = p_w[jAc * 4 + hsel];
      float pB = p_w[jBc * 4 + hsel];
      pA = vA ? pA : 0.f;
      pB = vB ? pB : 0.f;
      uint4 uA = hb[(size_t)sA * 16];
      uint4 uB = hb[(size_t)sB * 16];
      acc[0] = fmaf(pA, blo(uA.x), acc[0]); acc[1] = fmaf(pA, bhi(uA.x), acc[1]);
      acc[2] = fmaf(pA, blo(uA.y), acc[2]); acc[3] = fmaf(pA, bhi(uA.y), acc[3]);
      acc[4] = fmaf(pA, blo(uA.z), acc[4]); acc[5] = fmaf(pA, bhi(uA.z), acc[5]);
      acc[6] = fmaf(pA, blo(uA.w), acc[6]); acc[7] = fmaf(pA, bhi(uA.w), acc[7]);
      acc[0] = fmaf(pB, blo(uB.x), acc[0]); acc[1] = fmaf(pB, bhi(uB.x), acc[1]);
      acc[2] = fmaf(pB, blo(uB.y), acc[2]); acc[3] = fmaf(pB, bhi(uB.y), acc[3]);
      acc[4] = fmaf(pB, blo(uB.z), acc[4]); acc[5] = fmaf(pB, bhi(uB.z), acc[5]);
      acc[6] = fmaf(pB, blo(uB.w), acc[6]); acc[7] = fmaf(pB, bhi(uB.w), acc[7]);
    }
  }

  #pragma unroll
  for (int off = 32; off; off >>= 1) {
    z0 += __shfl_xor(z0, off);
    z1 += __shfl_xor(z1, off);
    z2 += __shfl_xor(z2, off);
    z3 += __shfl_xor(z3, off);
  }
  // combine the 4 quarter-wave partial sums (each holds different edges)
  #pragma unroll
  for (int k = 0; k < 8; ++k) {
    acc[k] += __shfl_xor(acc[k], 16);
    acc[k] += __shfl_xor(acc[k], 32);
  }
  if (lane < 16) {
    float zh = (hsel == 0) ? z0 : (hsel == 1) ? z1 : (hsel == 2) ? z2 : z3;
    float inv = 1.f / (zh + 1e-16f);
    int f0 = fl * 8;
    float4 b0 = *reinterpret_cast<const float4*>(bias + f0);
    float4 b1 = *reinterpret_cast<const float4*>(bias + f0 + 4);
    float o[8];
    o[0] = acc[0] * inv + b0.x; o[1] = acc[1] * inv + b0.y;
    o[2] = acc[2] * inv + b0.z; o[3] = acc[3] * inv + b0.w;
    o[4] = acc[4] * inv + b1.x; o[5] = acc[5] * inv + b1.y;
    o[6] = acc[6] * inv + b1.z; o[7] = acc[7] * inv + b1.w;
    if (ELU_OUT) {
      #pragma unroll
      for (int k = 0; k < 8; ++k) o[k] = o[k] > 0.f ? o[k] : expm1f(o[k]);
    }
    float* op = OUT + (size_t)dst * 128 + f0;
    *reinterpret_cast<float4*>(op) = make_float4(o[0], o[1], o[2], o[3]);
    *reinterpret_cast<float4*>(op + 4) = make_float4(o[4], o[5], o[6], o[7]);
  }
}

// ---------------- pooling (batch is sorted) ----------------
__global__ __launch_bounds__(256) void k_pool(
    const float* __restrict__ X, const int* __restrict__ batch,
    float* __restrict__ pooled, int* __restrict__ gcnt, int n) {
  int lane = threadIdx.x & 63;
  int w = blockIdx.x * 4 + (threadIdx.x >> 6);
  int a = w * 64;
  if (a >= n) return;
  int b = min(a + 64, n);
  float accA = 0.f, accB = 0.f;
  int gcur = batch[a];
  int cg = 0;
  for (int node = a; node < b; ++node) {
    int g = batch[node];
    if (g != gcur) {
      atomicAdd(&pooled[(size_t)gcur * 128 + lane], accA);
      atomicAdd(&pooled[(size_t)gcur * 128 + lane + 64], accB);
      if (lane == 0) atomicAdd(&gcnt[gcur], cg);
      accA = accB = 0.f; cg = 0; gcur = g;
    }
    accA += X[(size_t)node * 128 + lane];
    accB += X[(size_t)node * 128 + lane + 64];
    ++cg;
  }
  atomicAdd(&pooled[(size_t)gcur * 128 + lane], accA);
  atomicAdd(&pooled[(size_t)gcur * 128 + lane + 64], accB);
  if (lane == 0) atomicAdd(&gcnt[gcur], cg);
}

// ---------------- classifier head ----------------
__global__ void k_head(const float* __restrict__ pooled, const int* __restrict__ gcnt,
                       const float* __restrict__ Wl, const float* __restrict__ bl,
                       float* __restrict__ out) {
  int g = blockIdx.x;
  int lane = threadIdx.x;  // 64 threads
  float cnt = fmaxf((float)gcnt[g], 1.f);
  float pA = pooled[(size_t)g * 128 + lane] / cnt;
  float pB = pooled[(size_t)g * 128 + lane + 64] / cnt;
  float l[OUTC];
  #pragma unroll
  for (int o = 0; o < OUTC; ++o) {
    float s = pA * Wl[lane * OUTC + o] + pB * Wl[(lane + 64) * OUTC + o];
    #pragma unroll
    for (int off = 32; off; off >>= 1) s += __shfl_xor(s, off);
    l[o] = s + bl[o];
  }
  float mx = l[0];
  #pragma unroll
  for (int o = 1; o < OUTC; ++o) mx = fmaxf(mx, l[o]);
  float se = 0.f;
  #pragma unroll
  for (int o = 0; o < OUTC; ++o) { l[o] = __expf(l[o] - mx); se += l[o]; }
  if (lane == 0) {
    float inv = 1.f / se;
    #pragma unroll
    for (int o = 0; o < OUTC; ++o) out[g * OUTC + o] = l[o] * inv;
  }
}

extern "C" void kernel_launch(void* const* d_in, const int* in_sizes, int n_in,
                              void* d_out, int out_size, void* d_ws, size_t ws_size,
                              hipStream_t stream) {
  const float* x   = (const float*)d_in[0];
  const float* W1  = (const float*)d_in[1];
  const float* a1s = (const float*)d_in[2];
  const float* a1d = (const float*)d_in[3];
  const float* b1  = (const float*)d_in[4];
  const float* W2  = (const float*)d_in[5];
  const float* a2s = (const float*)d_in[6];
  const float* a2d = (const float*)d_in[7];
  const float* b2  = (const float*)d_in[8];
  const float* Wl  = (const float*)d_in[9];
  const float* bl  = (const float*)d_in[10];
  const int* ei    = (const int*)d_in[11];
  const int* batch = (const int*)d_in[12];
  const int N = in_sizes[12];
  const int E = in_sizes[11] / 2;
  const int G = out_size / OUTC;
  float* out = (float*)d_out;
  (void)n_in; (void)ws_size;

  char* w = (char*)d_ws;
  auto alloc = [&](size_t bytes) { char* p = w; w += (bytes + 255) & ~(size_t)255; return (void*)p; };
  __hip_bfloat16* H = (__hip_bfloat16*)alloc((size_t)N * FDIM * sizeof(__hip_bfloat16));
  float* ACT    = (float*)alloc((size_t)N * FDIM * sizeof(float));
  float* AS     = (float*)alloc((size_t)N * HEADS * sizeof(float));
  float* AD     = (float*)alloc((size_t)N * HEADS * sizeof(float));
  int*   deg    = (int*)alloc((size_t)N * sizeof(int));
  int*   offs   = (int*)alloc((size_t)(N + 1) * sizeof(int));
  int*   cur    = (int*)alloc((size_t)N * sizeof(int));
  int*   csr    = (int*)alloc((size_t)(E + N) * sizeof(int));
  int*   parts  = (int*)alloc(256 * sizeof(int));
  float* pooled = (float*)alloc((size_t)G * FDIM * sizeof(float));
  int*   gcnt   = (int*)alloc((size_t)G * sizeof(int));

  hipMemsetAsync(deg, 0, (size_t)N * sizeof(int), stream);
  hipMemsetAsync(cur, 0, (size_t)N * sizeof(int), stream);
  hipMemsetAsync(pooled, 0, (size_t)G * FDIM * sizeof(float), stream);
  hipMemsetAsync(gcnt, 0, (size_t)G * sizeof(int), stream);

  int tot = E + N;
  int eb = (tot + 255) / 256;
  int nb = (N + 255) / 256;
  k_count<<<eb, 256, 0, stream>>>(ei, deg, E, N);
  k_scan_block<<<nb, 256, 0, stream>>>(deg, offs, parts, N);
  k_scan_parts<<<1, 256, 0, stream>>>(parts, nb);
  k_add_offs<<<nb, 256, 0, stream>>>(offs, parts, N);
  k_fill<<<eb, 256, 0, stream>>>(ei, offs, cur, csr, E, N);

  int gb = (N + 63) / 64;
  int ab = (N + 3) / 4;
  k_gemm_al<<<gb, 256, 0, stream>>>(x, W1, a1s, a1d, H, AS, AD, N);
  k_agg<true><<<ab, 256, 0, stream>>>(H, AS, AD, offs, csr, b1, ACT, N);
  k_gemm_al<<<gb, 256, 0, stream>>>(ACT, W2, a2s, a2d, H, AS, AD, N);
  k_agg<false><<<ab, 256, 0, stream>>>(H, AS, AD, offs, csr, b2, ACT, N);

  int pb = (N + 255) / 256;
  k_pool<<<pb, 256, 0, stream>>>(ACT, batch, pooled, gcnt, N);
  k_head<<<G, 64, 0, stream>>>(pooled, gcnt, Wl, bl, out);
}

// Round 3
// 333.292 us; speedup vs baseline: 1.3546x; 1.2101x over previous
//
#include <hip/hip_runtime.h>
#include <hip/hip_bf16.h>
#include <math.h>

#define HEADS 4
#define HID 32
#define FDIM 128   // HEADS*HID == IN
#define OUTC 10
#define NEG 0.2f

typedef __attribute__((ext_vector_type(4))) float f32x4;
typedef __attribute__((ext_vector_type(8))) short bf16x8;

static __device__ __forceinline__ float lrelu(float v) { return v > 0.f ? v : NEG * v; }

// round-to-nearest-even f32 -> bf16 (returns low 16 bits)
static __device__ __forceinline__ unsigned bfr(float f) {
  unsigned u = __float_as_uint(f);
  return (u + 0x7fffu + ((u >> 16) & 1u)) >> 16;
}
static __device__ __forceinline__ float blo(unsigned u) { return __uint_as_float(u << 16); }
static __device__ __forceinline__ float bhi(unsigned u) { return __uint_as_float(u & 0xffff0000u); }

// ---------------- CSR build ----------------
__global__ void k_count(const int* __restrict__ ei, int* __restrict__ deg, int E, int n) {
  int e = blockIdx.x * 256 + threadIdx.x;
  int tot = E + n;
  if (e >= tot) return;
  int dst = (e < E) ? ei[E + e] : (e - E);
  atomicAdd(&deg[dst], 1);
}

__global__ void k_scan_block(const int* __restrict__ deg, int* __restrict__ offs,
                             int* __restrict__ parts, int n) {
  __shared__ int sh[256];
  int i = blockIdx.x * 256 + threadIdx.x;
  int v = (i < n) ? deg[i] : 0;
  sh[threadIdx.x] = v;
  __syncthreads();
  #pragma unroll
  for (int off = 1; off < 256; off <<= 1) {
    int t = (threadIdx.x >= off) ? sh[threadIdx.x - off] : 0;
    __syncthreads();
    sh[threadIdx.x] += t;
    __syncthreads();
  }
  if (i < n) offs[i + 1] = sh[threadIdx.x];
  if (threadIdx.x == 255) parts[blockIdx.x] = sh[255];
}

__global__ void k_scan_parts(int* __restrict__ parts, int nb) {
  __shared__ int sh[256];
  int v = (threadIdx.x < nb) ? parts[threadIdx.x] : 0;
  sh[threadIdx.x] = v;
  __syncthreads();
  #pragma unroll
  for (int off = 1; off < 256; off <<= 1) {
    int t = (threadIdx.x >= off) ? sh[threadIdx.x - off] : 0;
    __syncthreads();
    sh[threadIdx.x] += t;
    __syncthreads();
  }
  if (threadIdx.x < nb) parts[threadIdx.x] = sh[threadIdx.x] - v;  // exclusive prefix
}

__global__ void k_add_offs(int* __restrict__ offs, const int* __restrict__ parts, int n) {
  int i = blockIdx.x * 256 + threadIdx.x;
  if (i < n) offs[i + 1] += parts[blockIdx.x];
  if (i == 0) offs[0] = 0;
}

__global__ void k_fill(const int* __restrict__ ei, const int* __restrict__ offs,
                       int* __restrict__ cursor, int* __restrict__ csr, int E, int n) {
  int e = blockIdx.x * 256 + threadIdx.x;
  int tot = E + n;
  if (e >= tot) return;
  int src = (e < E) ? ei[e] : (e - E);
  int dst = (e < E) ? ei[E + e] : (e - E);
  int pos = atomicAdd(&cursor[dst], 1);
  csr[offs[dst] + pos] = src;
}

// ---------------- weight prep: pack W (+ Wa = W @ [a_src;a_dst]^T) into ----
// B-fragment layout for mfma_f32_16x16x32_bf16.
// WF[frag=t*9+ct][lane][j]: B[k = t*32 + (lane>>4)*8 + j][col],
//   ct<8: col = ct*16 + (lane&15) from W;  ct==8: col<8 -> Wa[k][col] else 0.
__global__ void k_prep(const float* __restrict__ W, const float* __restrict__ as_,
                       const float* __restrict__ ad_, uint4* __restrict__ WF) {
  int gid = blockIdx.x * 256 + threadIdx.x;  // 9*256 = 2304 = 36 frags * 64 lanes
  if (gid >= 2304) return;
  int lane = gid & 63, frag = gid >> 6;
  int t = frag / 9, ct = frag - t * 9;
  int quad = lane >> 4, r = lane & 15;
  int kbase = t * 32 + quad * 8;
  unsigned v[8];
  if (ct < 8) {
    int col = ct * 16 + r;
    #pragma unroll
    for (int j = 0; j < 8; ++j) v[j] = bfr(W[(size_t)(kbase + j) * 128 + col]);
  } else if (r < 8) {
    int h = r & 3;
    const float* av = (r < 4 ? as_ : ad_) + h * 32;
    #pragma unroll
    for (int j = 0; j < 8; ++j) {
      const float* wr = W + (size_t)(kbase + j) * 128 + h * 32;
      float s = 0.f;
      for (int c = 0; c < 32; ++c) s = fmaf(wr[c], av[c], s);
      v[j] = bfr(s);
    }
  } else {
    #pragma unroll
    for (int j = 0; j < 8; ++j) v[j] = 0;
  }
  uint4 pk;
  pk.x = v[0] | (v[1] << 16);
  pk.y = v[2] | (v[3] << 16);
  pk.z = v[4] | (v[5] << 16);
  pk.w = v[6] | (v[7] << 16);
  WF[gid] = pk;
}

// ---------------- MFMA GEMM + attention logits ----------------
// Block = 256 threads = 4 waves; wave w owns rows [blk*64 + w*16, +16).
// 9 col-tiles of 16: tiles 0..7 -> H (bf16), tile 8 cols 0..7 -> AL (f32,
// [n][8] = {src logits 0..3, dst logits 4..7}). B-frags staged in LDS.
__global__ __launch_bounds__(256) void k_mm(
    const float* __restrict__ X, const uint4* __restrict__ WF,
    unsigned short* __restrict__ H, float* __restrict__ AL, int n) {
  __shared__ uint4 wf[2304];
  int tid = threadIdx.x;
  #pragma unroll
  for (int i = 0; i < 9; ++i) wf[i * 256 + tid] = WF[i * 256 + tid];
  __syncthreads();
  int lane = tid & 63, wid = tid >> 6;
  int quad = lane >> 4, r = lane & 15;
  int rowbase = blockIdx.x * 64 + wid * 16;
  int arow = rowbase + r;
  int arowc = arow < n ? arow : 0;
  const float* xp = X + (size_t)arowc * 128 + quad * 8;
  const bf16x8* wfs = (const bf16x8*)wf;

  f32x4 acc[9];
  #pragma unroll
  for (int ct = 0; ct < 9; ++ct) acc[ct] = 0;

  #pragma unroll
  for (int t = 0; t < 4; ++t) {
    float4 x0 = *reinterpret_cast<const float4*>(xp + t * 32);
    float4 x1 = *reinterpret_cast<const float4*>(xp + t * 32 + 4);
    bf16x8 a;
    a[0] = (short)bfr(x0.x); a[1] = (short)bfr(x0.y);
    a[2] = (short)bfr(x0.z); a[3] = (short)bfr(x0.w);
    a[4] = (short)bfr(x1.x); a[5] = (short)bfr(x1.y);
    a[6] = (short)bfr(x1.z); a[7] = (short)bfr(x1.w);
    #pragma unroll
    for (int ct = 0; ct < 9; ++ct)
      acc[ct] = __builtin_amdgcn_mfma_f32_16x16x32_bf16(
          a, wfs[(t * 9 + ct) * 64 + lane], acc[ct], 0, 0, 0);
  }

  int orow0 = rowbase + quad * 4;
  #pragma unroll
  for (int rr = 0; rr < 4; ++rr) {
    int orow = orow0 + rr;
    if (orow < n) {
      unsigned short* hp = H + (size_t)orow * 128 + r;
      #pragma unroll
      for (int ct = 0; ct < 8; ++ct) hp[ct * 16] = (unsigned short)bfr(acc[ct][rr]);
      if (r < 8) AL[(size_t)orow * 8 + r] = acc[8][rr];
    }
  }
}

// ---------------- per-dst softmax + aggregation ----------------
// One wave per destination node; AL layout [n][8] = {src 0..3, dst 4..7}.
template<bool ELU_OUT>
__global__ __launch_bounds__(256) void k_agg(
    const unsigned short* __restrict__ H, const float* __restrict__ AL,
    const int* __restrict__ offs, const int* __restrict__ csr,
    const float* __restrict__ bias, float* __restrict__ OUT, int n) {
  __shared__ int s_l[4][64];
  __shared__ float p_l[4][64 * 4];
  int lane = threadIdx.x & 63;
  int wid = threadIdx.x >> 6;
  int dst = __builtin_amdgcn_readfirstlane(blockIdx.x * 4 + wid);
  if (dst >= n) return;
  int* s_w = s_l[wid];
  float* p_w = p_l[wid];
  int beg = offs[dst], end = offs[dst + 1];
  float4 adv = *reinterpret_cast<const float4*>(AL + (size_t)dst * 8 + 4);

  // ---- pass 1: per-head max ----
  float m0 = -1e30f, m1 = -1e30f, m2 = -1e30f, m3 = -1e30f;
  float e00 = -1e30f, e01 = -1e30f, e02 = -1e30f, e03 = -1e30f;
  int s0v = 0;
  for (int cb = beg; cb < end; cb += 64) {
    int idx = cb + lane;
    float e0 = -1e30f, e1 = -1e30f, e2 = -1e30f, e3 = -1e30f;
    int s = 0;
    if (idx < end) {
      s = csr[idx];
      float4 a = *reinterpret_cast<const float4*>(AL + (size_t)s * 8);
      e0 = lrelu(a.x + adv.x); e1 = lrelu(a.y + adv.y);
      e2 = lrelu(a.z + adv.z); e3 = lrelu(a.w + adv.w);
    }
    if (cb == beg) { e00 = e0; e01 = e1; e02 = e2; e03 = e3; s0v = s; }
    m0 = fmaxf(m0, e0); m1 = fmaxf(m1, e1); m2 = fmaxf(m2, e2); m3 = fmaxf(m3, e3);
  }
  #pragma unroll
  for (int off = 32; off; off >>= 1) {
    m0 = fmaxf(m0, __shfl_xor(m0, off));
    m1 = fmaxf(m1, __shfl_xor(m1, off));
    m2 = fmaxf(m2, __shfl_xor(m2, off));
    m3 = fmaxf(m3, __shfl_xor(m3, off));
  }

  // ---- pass 2: p, z, feature gather ----
  float z0 = 0.f, z1 = 0.f, z2 = 0.f, z3 = 0.f;
  float acc[8];
  #pragma unroll
  for (int k = 0; k < 8; ++k) acc[k] = 0.f;
  int fl = lane & 15;        // feature octet index (8 floats each)
  int qw = lane >> 4;        // quarter-wave = edge slot within group of 4
  int hsel = fl >> 2;        // head for this feature octet
  const uint4* hb = reinterpret_cast<const uint4*>(H) + fl;

  for (int cb = beg; cb < end; cb += 64) {
    int idx = cb + lane;
    bool v = idx < end;
    float e0, e1, e2, e3;
    int s;
    if (cb == beg) { e0 = e00; e1 = e01; e2 = e02; e3 = e03; s = s0v; }
    else {
      e0 = e1 = e2 = e3 = -1e30f; s = 0;
      if (v) {
        s = csr[idx];
        float4 a = *reinterpret_cast<const float4*>(AL + (size_t)s * 8);
        e0 = lrelu(a.x + adv.x); e1 = lrelu(a.y + adv.y);
        e2 = lrelu(a.z + adv.z); e3 = lrelu(a.w + adv.w);
      }
    }
    float p0 = v ? __expf(e0 - m0) : 0.f;
    float p1 = v ? __expf(e1 - m1) : 0.f;
    float p2 = v ? __expf(e2 - m2) : 0.f;
    float p3 = v ? __expf(e3 - m3) : 0.f;
    z0 += p0; z1 += p1; z2 += p2; z3 += p3;

    s_w[lane] = s;
    *reinterpret_cast<float4*>(&p_w[lane * 4]) = make_float4(p0, p1, p2, p3);
    // wave-private LDS: compiler inserts lgkmcnt wait; no barrier needed

    int cnt = min(64, end - cb);
    int git = (cnt + 7) >> 3;
    for (int it = 0; it < git; ++it) {
      int jA = it * 8 + qw;
      int jB = jA + 4;
      bool vA = jA < cnt, vB = jB < cnt;
      int jAc = vA ? jA : 0;
      int jBc = vB ? jB : 0;
      int sA = s_w[jAc];
      int sB = s_w[jBc];
      float pA = p_w[jAc * 4 + hsel];
      float pB = p_w[jBc * 4 + hsel];
      pA = vA ? pA : 0.f;
      pB = vB ? pB : 0.f;
      uint4 uA = hb[(size_t)sA * 16];
      uint4 uB = hb[(size_t)sB * 16];
      acc[0] = fmaf(pA, blo(uA.x), acc[0]); acc[1] = fmaf(pA, bhi(uA.x), acc[1]);
      acc[2] = fmaf(pA, blo(uA.y), acc[2]); acc[3] = fmaf(pA, bhi(uA.y), acc[3]);
      acc[4] = fmaf(pA, blo(uA.z), acc[4]); acc[5] = fmaf(pA, bhi(uA.z), acc[5]);
      acc[6] = fmaf(pA, blo(uA.w), acc[6]); acc[7] = fmaf(pA, bhi(uA.w), acc[7]);
      acc[0] = fmaf(pB, blo(uB.x), acc[0]); acc[1] = fmaf(pB, bhi(uB.x), acc[1]);
      acc[2] = fmaf(pB, blo(uB.y), acc[2]); acc[3] = fmaf(pB, bhi(uB.y), acc[3]);
      acc[4] = fmaf(pB, blo(uB.z), acc[4]); acc[5] = fmaf(pB, bhi(uB.z), acc[5]);
      acc[6] = fmaf(pB, blo(uB.w), acc[6]); acc[7] = fmaf(pB, bhi(uB.w), acc[7]);
    }
  }

  #pragma unroll
  for (int off = 32; off; off >>= 1) {
    z0 += __shfl_xor(z0, off);
    z1 += __shfl_xor(z1, off);
    z2 += __shfl_xor(z2, off);
    z3 += __shfl_xor(z3, off);
  }
  // combine the 4 quarter-wave partial sums (each holds different edges)
  #pragma unroll
  for (int k = 0; k < 8; ++k) {
    acc[k] += __shfl_xor(acc[k], 16);
    acc[k] += __shfl_xor(acc[k], 32);
  }
  if (lane < 16) {
    float zh = (hsel == 0) ? z0 : (hsel == 1) ? z1 : (hsel == 2) ? z2 : z3;
    float inv = 1.f / (zh + 1e-16f);
    int f0 = fl * 8;
    float4 b0 = *reinterpret_cast<const float4*>(bias + f0);
    float4 b1 = *reinterpret_cast<const float4*>(bias + f0 + 4);
    float o[8];
    o[0] = acc[0] * inv + b0.x; o[1] = acc[1] * inv + b0.y;
    o[2] = acc[2] * inv + b0.z; o[3] = acc[3] * inv + b0.w;
    o[4] = acc[4] * inv + b1.x; o[5] = acc[5] * inv + b1.y;
    o[6] = acc[6] * inv + b1.z; o[7] = acc[7] * inv + b1.w;
    if (ELU_OUT) {
      #pragma unroll
      for (int k = 0; k < 8; ++k) o[k] = o[k] > 0.f ? o[k] : expm1f(o[k]);
    }
    float* op = OUT + (size_t)dst * 128 + f0;
    *reinterpret_cast<float4*>(op) = make_float4(o[0], o[1], o[2], o[3]);
    *reinterpret_cast<float4*>(op + 4) = make_float4(o[4], o[5], o[6], o[7]);
  }
}

// ---------------- pooling (batch is sorted) ----------------
__global__ __launch_bounds__(256) void k_pool(
    const float* __restrict__ X, const int* __restrict__ batch,
    float* __restrict__ pooled, int* __restrict__ gcnt, int n) {
  int lane = threadIdx.x & 63;
  int w = blockIdx.x * 4 + (threadIdx.x >> 6);
  int a = w * 64;
  if (a >= n) return;
  int b = min(a + 64, n);
  float accA = 0.f, accB = 0.f;
  int gcur = batch[a];
  int cg = 0;
  for (int node = a; node < b; ++node) {
    int g = batch[node];
    if (g != gcur) {
      atomicAdd(&pooled[(size_t)gcur * 128 + lane], accA);
      atomicAdd(&pooled[(size_t)gcur * 128 + lane + 64], accB);
      if (lane == 0) atomicAdd(&gcnt[gcur], cg);
      accA = accB = 0.f; cg = 0; gcur = g;
    }
    accA += X[(size_t)node * 128 + lane];
    accB += X[(size_t)node * 128 + lane + 64];
    ++cg;
  }
  atomicAdd(&pooled[(size_t)gcur * 128 + lane], accA);
  atomicAdd(&pooled[(size_t)gcur * 128 + lane + 64], accB);
  if (lane == 0) atomicAdd(&gcnt[gcur], cg);
}

// ---------------- classifier head ----------------
__global__ void k_head(const float* __restrict__ pooled, const int* __restrict__ gcnt,
                       const float* __restrict__ Wl, const float* __restrict__ bl,
                       float* __restrict__ out) {
  int g = blockIdx.x;
  int lane = threadIdx.x;  // 64 threads
  float cnt = fmaxf((float)gcnt[g], 1.f);
  float pA = pooled[(size_t)g * 128 + lane] / cnt;
  float pB = pooled[(size_t)g * 128 + lane + 64] / cnt;
  float l[OUTC];
  #pragma unroll
  for (int o = 0; o < OUTC; ++o) {
    float s = pA * Wl[lane * OUTC + o] + pB * Wl[(lane + 64) * OUTC + o];
    #pragma unroll
    for (int off = 32; off; off >>= 1) s += __shfl_xor(s, off);
    l[o] = s + bl[o];
  }
  float mx = l[0];
  #pragma unroll
  for (int o = 1; o < OUTC; ++o) mx = fmaxf(mx, l[o]);
  float se = 0.f;
  #pragma unroll
  for (int o = 0; o < OUTC; ++o) { l[o] = __expf(l[o] - mx); se += l[o]; }
  if (lane == 0) {
    float inv = 1.f / se;
    #pragma unroll
    for (int o = 0; o < OUTC; ++o) out[g * OUTC + o] = l[o] * inv;
  }
}

extern "C" void kernel_launch(void* const* d_in, const int* in_sizes, int n_in,
                              void* d_out, int out_size, void* d_ws, size_t ws_size,
                              hipStream_t stream) {
  const float* x   = (const float*)d_in[0];
  const float* W1  = (const float*)d_in[1];
  const float* a1s = (const float*)d_in[2];
  const float* a1d = (const float*)d_in[3];
  const float* b1  = (const float*)d_in[4];
  const float* W2  = (const float*)d_in[5];
  const float* a2s = (const float*)d_in[6];
  const float* a2d = (const float*)d_in[7];
  const float* b2  = (const float*)d_in[8];
  const float* Wl  = (const float*)d_in[9];
  const float* bl  = (const float*)d_in[10];
  const int* ei    = (const int*)d_in[11];
  const int* batch = (const int*)d_in[12];
  const int N = in_sizes[12];
  const int E = in_sizes[11] / 2;
  const int G = out_size / OUTC;
  float* out = (float*)d_out;
  (void)n_in; (void)ws_size;

  char* w = (char*)d_ws;
  auto alloc = [&](size_t bytes) { char* p = w; w += (bytes + 255) & ~(size_t)255; return (void*)p; };
  unsigned short* H = (unsigned short*)alloc((size_t)N * FDIM * sizeof(unsigned short));
  float* ACT    = (float*)alloc((size_t)N * FDIM * sizeof(float));
  float* AL     = (float*)alloc((size_t)N * 8 * sizeof(float));
  uint4* WF1    = (uint4*)alloc(2304 * sizeof(uint4));
  uint4* WF2    = (uint4*)alloc(2304 * sizeof(uint4));
  int*   offs   = (int*)alloc((size_t)(N + 1) * sizeof(int));
  int*   csr    = (int*)alloc((size_t)(E + N) * sizeof(int));
  int*   parts  = (int*)alloc(256 * sizeof(int));
  // zero-init region: deg, cur, gcnt, pooled contiguous -> one memset
  char* z0 = w;
  int*   deg    = (int*)alloc((size_t)N * sizeof(int));
  int*   cur    = (int*)alloc((size_t)N * sizeof(int));
  int*   gcnt   = (int*)alloc((size_t)G * sizeof(int));
  float* pooled = (float*)alloc((size_t)G * FDIM * sizeof(float));
  size_t zbytes = (size_t)(w - z0);
  hipMemsetAsync(z0, 0, zbytes, stream);

  int tot = E + N;
  int eb = (tot + 255) / 256;
  int nb = (N + 255) / 256;
  k_count<<<eb, 256, 0, stream>>>(ei, deg, E, N);
  k_scan_block<<<nb, 256, 0, stream>>>(deg, offs, parts, N);
  k_scan_parts<<<1, 256, 0, stream>>>(parts, nb);
  k_add_offs<<<nb, 256, 0, stream>>>(offs, parts, N);
  k_fill<<<eb, 256, 0, stream>>>(ei, offs, cur, csr, E, N);

  k_prep<<<9, 256, 0, stream>>>(W1, a1s, a1d, WF1);
  k_prep<<<9, 256, 0, stream>>>(W2, a2s, a2d, WF2);

  int gb = (N + 63) / 64;
  int ab = (N + 3) / 4;
  k_mm<<<gb, 256, 0, stream>>>(x, WF1, H, AL, N);
  k_agg<true><<<ab, 256, 0, stream>>>(H, AL, offs, csr, b1, ACT, N);
  k_mm<<<gb, 256, 0, stream>>>(ACT, WF2, H, AL, N);
  k_agg<false><<<ab, 256, 0, stream>>>(H, AL, offs, csr, b2, ACT, N);

  int pb = (N + 255) / 256;
  k_pool<<<pb, 256, 0, stream>>>(ACT, batch, pooled, gcnt, N);
  k_head<<<G, 64, 0, stream>>>(pooled, gcnt, Wl, bl, out);
}

// Round 4
// 298.528 us; speedup vs baseline: 1.5123x; 1.1165x over previous
//
#include <hip/hip_runtime.h>
#include <hip/hip_bf16.h>
#include <math.h>

#define HEADS 4
#define HID 32
#define FDIM 128   // HEADS*HID == IN
#define OUTC 10
#define NEG 0.2f

typedef __attribute__((ext_vector_type(4))) float f32x4;
typedef __attribute__((ext_vector_type(8))) short bf16x8;

static __device__ __forceinline__ float lrelu(float v) { return v > 0.f ? v : NEG * v; }

// round-to-nearest-even f32 -> bf16 (returns low 16 bits)
static __device__ __forceinline__ unsigned bfr(float f) {
  unsigned u = __float_as_uint(f);
  return (u + 0x7fffu + ((u >> 16) & 1u)) >> 16;
}
static __device__ __forceinline__ float blo(unsigned u) { return __uint_as_float(u << 16); }
static __device__ __forceinline__ float bhi(unsigned u) { return __uint_as_float(u & 0xffff0000u); }

// ---------------- CSR build ----------------
__global__ void k_count(const int* __restrict__ ei, int* __restrict__ deg, int E, int n) {
  int e = blockIdx.x * 256 + threadIdx.x;
  int tot = E + n;
  if (e >= tot) return;
  int dst = (e < E) ? ei[E + e] : (e - E);
  atomicAdd(&deg[dst], 1);
}

__global__ void k_scan_block(const int* __restrict__ deg, int* __restrict__ offs,
                             int* __restrict__ parts, int n) {
  __shared__ int sh[256];
  int i = blockIdx.x * 256 + threadIdx.x;
  int v = (i < n) ? deg[i] : 0;
  sh[threadIdx.x] = v;
  __syncthreads();
  #pragma unroll
  for (int off = 1; off < 256; off <<= 1) {
    int t = (threadIdx.x >= off) ? sh[threadIdx.x - off] : 0;
    __syncthreads();
    sh[threadIdx.x] += t;
    __syncthreads();
  }
  if (i < n) offs[i + 1] = sh[threadIdx.x];
  if (threadIdx.x == 255) parts[blockIdx.x] = sh[255];
}

__global__ void k_scan_parts(int* __restrict__ parts, int nb) {
  __shared__ int sh[256];
  int v = (threadIdx.x < nb) ? parts[threadIdx.x] : 0;
  sh[threadIdx.x] = v;
  __syncthreads();
  #pragma unroll
  for (int off = 1; off < 256; off <<= 1) {
    int t = (threadIdx.x >= off) ? sh[threadIdx.x - off] : 0;
    __syncthreads();
    sh[threadIdx.x] += t;
    __syncthreads();
  }
  if (threadIdx.x < nb) parts[threadIdx.x] = sh[threadIdx.x] - v;  // exclusive prefix
}

__global__ void k_add_offs(int* __restrict__ offs, const int* __restrict__ parts, int n) {
  int i = blockIdx.x * 256 + threadIdx.x;
  if (i < n) offs[i + 1] += parts[blockIdx.x];
  if (i == 0) offs[0] = 0;
}

__global__ void k_fill(const int* __restrict__ ei, const int* __restrict__ offs,
                       int* __restrict__ cursor, int* __restrict__ csr, int E, int n) {
  int e = blockIdx.x * 256 + threadIdx.x;
  int tot = E + n;
  if (e >= tot) return;
  int src = (e < E) ? ei[e] : (e - E);
  int dst = (e < E) ? ei[E + e] : (e - E);
  int pos = atomicAdd(&cursor[dst], 1);
  csr[offs[dst] + pos] = src;
}

// ---------------- Wa = W @ [a_src; a_dst]^T  (128 x 8, f32) ----------------
// grid 8 (c), block 128 (k): 1024 independent length-32 dots, float4 loads.
__global__ void k_wa(const float* __restrict__ W, const float* __restrict__ as_,
                     const float* __restrict__ ad_, float* __restrict__ Wa) {
  int c = blockIdx.x;       // 0..7: 0-3 src heads, 4-7 dst heads
  int k = threadIdx.x;      // 0..127
  int h = c & 3;
  const float* av = (c < 4 ? as_ : ad_) + h * 32;
  const float* wr = W + (size_t)k * 128 + h * 32;
  float s = 0.f;
  #pragma unroll
  for (int j = 0; j < 32; j += 4) {
    float4 wv = *reinterpret_cast<const float4*>(wr + j);
    float4 a4 = *reinterpret_cast<const float4*>(av + j);
    s += wv.x * a4.x + wv.y * a4.y + wv.z * a4.z + wv.w * a4.w;
  }
  Wa[k * 8 + c] = s;
}

// ---------------- weight prep: pack W + Wa into B-fragment layout ----------
// for mfma_f32_16x16x32_bf16.
// WF[frag=t*9+ct][lane][j]: B[k = t*32 + (lane>>4)*8 + j][col],
//   ct<8: col = ct*16 + (lane&15) from W;  ct==8: col<8 -> Wa[k][col] else 0.
__global__ void k_prep(const float* __restrict__ W, const float* __restrict__ Wa,
                       uint4* __restrict__ WF) {
  int gid = blockIdx.x * 256 + threadIdx.x;  // 9*256 = 2304 = 36 frags * 64 lanes
  if (gid >= 2304) return;
  int lane = gid & 63, frag = gid >> 6;
  int t = frag / 9, ct = frag - t * 9;
  int quad = lane >> 4, r = lane & 15;
  int kbase = t * 32 + quad * 8;
  unsigned v[8];
  if (ct < 8) {
    int col = ct * 16 + r;
    #pragma unroll
    for (int j = 0; j < 8; ++j) v[j] = bfr(W[(size_t)(kbase + j) * 128 + col]);
  } else if (r < 8) {
    #pragma unroll
    for (int j = 0; j < 8; ++j) v[j] = bfr(Wa[(kbase + j) * 8 + r]);
  } else {
    #pragma unroll
    for (int j = 0; j < 8; ++j) v[j] = 0;
  }
  uint4 pk;
  pk.x = v[0] | (v[1] << 16);
  pk.y = v[2] | (v[3] << 16);
  pk.z = v[4] | (v[5] << 16);
  pk.w = v[6] | (v[7] << 16);
  WF[gid] = pk;
}

// ---------------- MFMA GEMM + attention logits ----------------
// Block = 256 threads = 4 waves; wave w owns rows [blk*64 + w*16, +16).
// 9 col-tiles of 16: tiles 0..7 -> H (bf16), tile 8 cols 0..7 -> AL (f32,
// [n][8] = {src logits 0..3, dst logits 4..7}). B-frags staged in LDS.
__global__ __launch_bounds__(256) void k_mm(
    const float* __restrict__ X, const uint4* __restrict__ WF,
    unsigned short* __restrict__ H, float* __restrict__ AL, int n) {
  __shared__ uint4 wf[2304];
  int tid = threadIdx.x;
  #pragma unroll
  for (int i = 0; i < 9; ++i) wf[i * 256 + tid] = WF[i * 256 + tid];
  __syncthreads();
  int lane = tid & 63, wid = tid >> 6;
  int quad = lane >> 4, r = lane & 15;
  int rowbase = blockIdx.x * 64 + wid * 16;
  int arow = rowbase + r;
  int arowc = arow < n ? arow : 0;
  const float* xp = X + (size_t)arowc * 128 + quad * 8;
  const bf16x8* wfs = (const bf16x8*)wf;

  f32x4 acc[9];
  #pragma unroll
  for (int ct = 0; ct < 9; ++ct) acc[ct] = 0;

  #pragma unroll
  for (int t = 0; t < 4; ++t) {
    float4 x0 = *reinterpret_cast<const float4*>(xp + t * 32);
    float4 x1 = *reinterpret_cast<const float4*>(xp + t * 32 + 4);
    bf16x8 a;
    a[0] = (short)bfr(x0.x); a[1] = (short)bfr(x0.y);
    a[2] = (short)bfr(x0.z); a[3] = (short)bfr(x0.w);
    a[4] = (short)bfr(x1.x); a[5] = (short)bfr(x1.y);
    a[6] = (short)bfr(x1.z); a[7] = (short)bfr(x1.w);
    #pragma unroll
    for (int ct = 0; ct < 9; ++ct)
      acc[ct] = __builtin_amdgcn_mfma_f32_16x16x32_bf16(
          a, wfs[(t * 9 + ct) * 64 + lane], acc[ct], 0, 0, 0);
  }

  int orow0 = rowbase + quad * 4;
  #pragma unroll
  for (int rr = 0; rr < 4; ++rr) {
    int orow = orow0 + rr;
    if (orow < n) {
      unsigned short* hp = H + (size_t)orow * 128 + r;
      #pragma unroll
      for (int ct = 0; ct < 8; ++ct) hp[ct * 16] = (unsigned short)bfr(acc[ct][rr]);
      if (r < 8) AL[(size_t)orow * 8 + r] = acc[8][rr];
    }
  }
}

// ---------------- per-dst softmax + aggregation (single pass) ----------------
// One wave per destination node; AL layout [n][8] = {src 0..3, dst 4..7}.
// No max-stabilization: logits are O(1) here (exp(e)/sum == exp(e-m)/sum
// mathematically; f32 overflow needs e>88, impossible for this model scale).
template<bool ELU_OUT>
__global__ __launch_bounds__(256) void k_agg(
    const unsigned short* __restrict__ H, const float* __restrict__ AL,
    const int* __restrict__ offs, const int* __restrict__ csr,
    const float* __restrict__ bias, float* __restrict__ OUT, int n) {
  __shared__ int s_l[4][64];
  __shared__ float p_l[4][64 * 4];
  int lane = threadIdx.x & 63;
  int wid = threadIdx.x >> 6;
  int dst = __builtin_amdgcn_readfirstlane(blockIdx.x * 4 + wid);
  if (dst >= n) return;
  int* s_w = s_l[wid];
  float* p_w = p_l[wid];
  int beg = offs[dst], end = offs[dst + 1];
  float4 adv = *reinterpret_cast<const float4*>(AL + (size_t)dst * 8 + 4);

  float z0 = 0.f, z1 = 0.f, z2 = 0.f, z3 = 0.f;
  float acc[8];
  #pragma unroll
  for (int k = 0; k < 8; ++k) acc[k] = 0.f;
  int fl = lane & 15;        // feature octet index (8 floats each)
  int qw = lane >> 4;        // quarter-wave = edge slot within group of 4
  int hsel = fl >> 2;        // head for this feature octet
  const uint4* hb = reinterpret_cast<const uint4*>(H) + fl;

  for (int cb = beg; cb < end; cb += 64) {
    int idx = cb + lane;
    bool v = idx < end;
    int s = 0;
    float p0 = 0.f, p1 = 0.f, p2 = 0.f, p3 = 0.f;
    if (v) {
      s = csr[idx];
      float4 a = *reinterpret_cast<const float4*>(AL + (size_t)s * 8);
      p0 = __expf(lrelu(a.x + adv.x));
      p1 = __expf(lrelu(a.y + adv.y));
      p2 = __expf(lrelu(a.z + adv.z));
      p3 = __expf(lrelu(a.w + adv.w));
    }
    z0 += p0; z1 += p1; z2 += p2; z3 += p3;

    s_w[lane] = s;
    *reinterpret_cast<float4*>(&p_w[lane * 4]) = make_float4(p0, p1, p2, p3);
    // wave-private LDS: compiler inserts lgkmcnt wait; no barrier needed

    int cnt = min(64, end - cb);
    int git = (cnt + 7) >> 3;
    for (int it = 0; it < git; ++it) {
      int jA = it * 8 + qw;
      int jB = jA + 4;
      bool vA = jA < cnt, vB = jB < cnt;
      int jAc = vA ? jA : 0;
      int jBc = vB ? jB : 0;
      int sA = s_w[jAc];
      int sB = s_w[jBc];
      float pA = p_w[jAc * 4 + hsel];
      float pB = p_w[jBc * 4 + hsel];
      pA = vA ? pA : 0.f;
      pB = vB ? pB : 0.f;
      uint4 uA = hb[(size_t)sA * 16];
      uint4 uB = hb[(size_t)sB * 16];
      acc[0] = fmaf(pA, blo(uA.x), acc[0]); acc[1] = fmaf(pA, bhi(uA.x), acc[1]);
      acc[2] = fmaf(pA, blo(uA.y), acc[2]); acc[3] = fmaf(pA, bhi(uA.y), acc[3]);
      acc[4] = fmaf(pA, blo(uA.z), acc[4]); acc[5] = fmaf(pA, bhi(uA.z), acc[5]);
      acc[6] = fmaf(pA, blo(uA.w), acc[6]); acc[7] = fmaf(pA, bhi(uA.w), acc[7]);
      acc[0] = fmaf(pB, blo(uB.x), acc[0]); acc[1] = fmaf(pB, bhi(uB.x), acc[1]);
      acc[2] = fmaf(pB, blo(uB.y), acc[2]); acc[3] = fmaf(pB, bhi(uB.y), acc[3]);
      acc[4] = fmaf(pB, blo(uB.z), acc[4]); acc[5] = fmaf(pB, bhi(uB.z), acc[5]);
      acc[6] = fmaf(pB, blo(uB.w), acc[6]); acc[7] = fmaf(pB, bhi(uB.w), acc[7]);
    }
  }

  #pragma unroll
  for (int off = 32; off; off >>= 1) {
    z0 += __shfl_xor(z0, off);
    z1 += __shfl_xor(z1, off);
    z2 += __shfl_xor(z2, off);
    z3 += __shfl_xor(z3, off);
  }
  // combine the 4 quarter-wave partial sums (each holds different edges)
  #pragma unroll
  for (int k = 0; k < 8; ++k) {
    acc[k] += __shfl_xor(acc[k], 16);
    acc[k] += __shfl_xor(acc[k], 32);
  }
  if (lane < 16) {
    float zh = (hsel == 0) ? z0 : (hsel == 1) ? z1 : (hsel == 2) ? z2 : z3;
    float inv = 1.f / (zh + 1e-16f);
    int f0 = fl * 8;
    float4 b0 = *reinterpret_cast<const float4*>(bias + f0);
    float4 b1 = *reinterpret_cast<const float4*>(bias + f0 + 4);
    float o[8];
    o[0] = acc[0] * inv + b0.x; o[1] = acc[1] * inv + b0.y;
    o[2] = acc[2] * inv + b0.z; o[3] = acc[3] * inv + b0.w;
    o[4] = acc[4] * inv + b1.x; o[5] = acc[5] * inv + b1.y;
    o[6] = acc[6] * inv + b1.z; o[7] = acc[7] * inv + b1.w;
    if (ELU_OUT) {
      #pragma unroll
      for (int k = 0; k < 8; ++k) o[k] = o[k] > 0.f ? o[k] : expm1f(o[k]);
    }
    float* op = OUT + (size_t)dst * 128 + f0;
    *reinterpret_cast<float4*>(op) = make_float4(o[0], o[1], o[2], o[3]);
    *reinterpret_cast<float4*>(op + 4) = make_float4(o[4], o[5], o[6], o[7]);
  }
}

// ---------------- pooling (batch is sorted) ----------------
// 4-node unrolled fast path: sorted batch => batch[node+3]==gcur implies
// all four nodes belong to gcur; 8 independent loads in flight.
__global__ __launch_bounds__(256) void k_pool(
    const float* __restrict__ X, const int* __restrict__ batch,
    float* __restrict__ pooled, int* __restrict__ gcnt, int n) {
  int lane = threadIdx.x & 63;
  int w = blockIdx.x * 4 + (threadIdx.x >> 6);
  int a = w * 64;
  if (a >= n) return;
  int b = min(a + 64, n);
  float accA = 0.f, accB = 0.f;
  int gcur = batch[a];
  int cg = 0;
  int node = a;
  while (node < b) {
    if (node + 4 <= b && batch[node + 3] == gcur) {
      float sA0 = X[(size_t)(node + 0) * 128 + lane];
      float sB0 = X[(size_t)(node + 0) * 128 + lane + 64];
      float sA1 = X[(size_t)(node + 1) * 128 + lane];
      float sB1 = X[(size_t)(node + 1) * 128 + lane + 64];
      float sA2 = X[(size_t)(node + 2) * 128 + lane];
      float sB2 = X[(size_t)(node + 2) * 128 + lane + 64];
      float sA3 = X[(size_t)(node + 3) * 128 + lane];
      float sB3 = X[(size_t)(node + 3) * 128 + lane + 64];
      accA += (sA0 + sA1) + (sA2 + sA3);
      accB += (sB0 + sB1) + (sB2 + sB3);
      cg += 4; node += 4;
      continue;
    }
    int g = batch[node];
    if (g != gcur) {
      atomicAdd(&pooled[(size_t)gcur * 128 + lane], accA);
      atomicAdd(&pooled[(size_t)gcur * 128 + lane + 64], accB);
      if (lane == 0) atomicAdd(&gcnt[gcur], cg);
      accA = accB = 0.f; cg = 0; gcur = g;
    }
    accA += X[(size_t)node * 128 + lane];
    accB += X[(size_t)node * 128 + lane + 64];
    ++cg; ++node;
  }
  atomicAdd(&pooled[(size_t)gcur * 128 + lane], accA);
  atomicAdd(&pooled[(size_t)gcur * 128 + lane + 64], accB);
  if (lane == 0) atomicAdd(&gcnt[gcur], cg);
}

// ---------------- classifier head ----------------
__global__ void k_head(const float* __restrict__ pooled, const int* __restrict__ gcnt,
                       const float* __restrict__ Wl, const float* __restrict__ bl,
                       float* __restrict__ out) {
  int g = blockIdx.x;
  int lane = threadIdx.x;  // 64 threads
  float cnt = fmaxf((float)gcnt[g], 1.f);
  float pA = pooled[(size_t)g * 128 + lane] / cnt;
  float pB = pooled[(size_t)g * 128 + lane + 64] / cnt;
  float l[OUTC];
  #pragma unroll
  for (int o = 0; o < OUTC; ++o) {
    float s = pA * Wl[lane * OUTC + o] + pB * Wl[(lane + 64) * OUTC + o];
    #pragma unroll
    for (int off = 32; off; off >>= 1) s += __shfl_xor(s, off);
    l[o] = s + bl[o];
  }
  float mx = l[0];
  #pragma unroll
  for (int o = 1; o < OUTC; ++o) mx = fmaxf(mx, l[o]);
  float se = 0.f;
  #pragma unroll
  for (int o = 0; o < OUTC; ++o) { l[o] = __expf(l[o] - mx); se += l[o]; }
  if (lane == 0) {
    float inv = 1.f / se;
    #pragma unroll
    for (int o = 0; o < OUTC; ++o) out[g * OUTC + o] = l[o] * inv;
  }
}

extern "C" void kernel_launch(void* const* d_in, const int* in_sizes, int n_in,
                              void* d_out, int out_size, void* d_ws, size_t ws_size,
                              hipStream_t stream) {
  const float* x   = (const float*)d_in[0];
  const float* W1  = (const float*)d_in[1];
  const float* a1s = (const float*)d_in[2];
  const float* a1d = (const float*)d_in[3];
  const float* b1  = (const float*)d_in[4];
  const float* W2  = (const float*)d_in[5];
  const float* a2s = (const float*)d_in[6];
  const float* a2d = (const float*)d_in[7];
  const float* b2  = (const float*)d_in[8];
  const float* Wl  = (const float*)d_in[9];
  const float* bl  = (const float*)d_in[10];
  const int* ei    = (const int*)d_in[11];
  const int* batch = (const int*)d_in[12];
  const int N = in_sizes[12];
  const int E = in_sizes[11] / 2;
  const int G = out_size / OUTC;
  float* out = (float*)d_out;
  (void)n_in; (void)ws_size;

  char* w = (char*)d_ws;
  auto alloc = [&](size_t bytes) { char* p = w; w += (bytes + 255) & ~(size_t)255; return (void*)p; };
  unsigned short* H = (unsigned short*)alloc((size_t)N * FDIM * sizeof(unsigned short));
  float* ACT    = (float*)alloc((size_t)N * FDIM * sizeof(float));
  float* AL     = (float*)alloc((size_t)N * 8 * sizeof(float));
  uint4* WF1    = (uint4*)alloc(2304 * sizeof(uint4));
  uint4* WF2    = (uint4*)alloc(2304 * sizeof(uint4));
  float* Wa     = (float*)alloc(128 * 8 * sizeof(float));
  int*   offs   = (int*)alloc((size_t)(N + 1) * sizeof(int));
  int*   csr    = (int*)alloc((size_t)(E + N) * sizeof(int));
  int*   parts  = (int*)alloc(256 * sizeof(int));
  // zero-init region: deg, cur, gcnt, pooled contiguous -> one memset
  char* z0 = w;
  int*   deg    = (int*)alloc((size_t)N * sizeof(int));
  int*   cur    = (int*)alloc((size_t)N * sizeof(int));
  int*   gcnt   = (int*)alloc((size_t)G * sizeof(int));
  float* pooled = (float*)alloc((size_t)G * FDIM * sizeof(float));
  size_t zbytes = (size_t)(w - z0);
  hipMemsetAsync(z0, 0, zbytes, stream);

  // weight prep first (independent of CSR)
  k_wa<<<8, 128, 0, stream>>>(W1, a1s, a1d, Wa);
  k_prep<<<9, 256, 0, stream>>>(W1, Wa, WF1);
  k_wa<<<8, 128, 0, stream>>>(W2, a2s, a2d, Wa);
  k_prep<<<9, 256, 0, stream>>>(W2, Wa, WF2);

  int tot = E + N;
  int eb = (tot + 255) / 256;
  int nb = (N + 255) / 256;
  k_count<<<eb, 256, 0, stream>>>(ei, deg, E, N);
  k_scan_block<<<nb, 256, 0, stream>>>(deg, offs, parts, N);
  k_scan_parts<<<1, 256, 0, stream>>>(parts, nb);
  k_add_offs<<<nb, 256, 0, stream>>>(offs, parts, N);
  k_fill<<<eb, 256, 0, stream>>>(ei, offs, cur, csr, E, N);

  int gb = (N + 63) / 64;
  int ab = (N + 3) / 4;
  k_mm<<<gb, 256, 0, stream>>>(x, WF1, H, AL, N);
  k_agg<true><<<ab, 256, 0, stream>>>(H, AL, offs, csr, b1, ACT, N);
  k_mm<<<gb, 256, 0, stream>>>(ACT, WF2, H, AL, N);
  k_agg<false><<<ab, 256, 0, stream>>>(H, AL, offs, csr, b2, ACT, N);

  int pb = (N + 255) / 256;
  k_pool<<<pb, 256, 0, stream>>>(ACT, batch, pooled, gcnt, N);
  k_head<<<G, 64, 0, stream>>>(pooled, gcnt, Wl, bl, out);
}